// Round 2
// baseline (373.626 us; speedup 1.0000x reference)
//
#include <hip/hip_runtime.h>
#include <stdint.h>

// Problem constants (B=4, S=2048, H=1024, E=8, TOP_K=2). All I/O fp32.
#define N_TOK 8192
#define H_DIM 1024
#define N_EXP 8

typedef __bf16 bf16x8 __attribute__((ext_vector_type(8)));
typedef float floatx4 __attribute__((ext_vector_type(4)));

static __device__ __forceinline__ unsigned short f2b(float f) {
    union { float f; unsigned int i; } v; v.f = f;
    unsigned int u = v.i;
    return (unsigned short)((u + 0x7FFFu + ((u >> 16) & 1u)) >> 16);
}

// ---------------- K1: router (1 wave per token, fp32) + tokens->bf16 ----------------
__global__ __launch_bounds__(256) void k_router(
    const float* __restrict__ tokens,
    const float* __restrict__ router_w,
    const float* __restrict__ router_b,
    int* __restrict__ cnt, int* __restrict__ bucket, float* __restrict__ w_arr,
    unsigned short* __restrict__ tokb)
{
    const int wave = threadIdx.x >> 6;
    const int lane = threadIdx.x & 63;
    const int n = blockIdx.x * 4 + wave;

    // lane handles 16 contiguous h values
    const float* xp = tokens + (size_t)n * H_DIM + lane * 16;
    float x[16];
#pragma unroll
    for (int i = 0; i < 4; ++i) {
        float4 v = *(const float4*)(xp + i * 4);
        x[i * 4 + 0] = v.x; x[i * 4 + 1] = v.y; x[i * 4 + 2] = v.z; x[i * 4 + 3] = v.w;
    }

    // emit bf16 copy of the token row (coalesced 32 B/lane)
    {
        unsigned short xb[16];
#pragma unroll
        for (int j = 0; j < 16; ++j) xb[j] = f2b(x[j]);
        unsigned short* dp = tokb + (size_t)n * H_DIM + lane * 16;
        *(uint4*)(dp)     = *(uint4*)(xb);
        *(uint4*)(dp + 8) = *(uint4*)(xb + 8);
    }

    float acc[N_EXP];
#pragma unroll
    for (int e = 0; e < N_EXP; ++e) {
        const float* wp = router_w + e * H_DIM + lane * 16;
        float s = 0.f;
#pragma unroll
        for (int i = 0; i < 4; ++i) {
            float4 v = *(const float4*)(wp + i * 4);
            s += x[i * 4 + 0] * v.x + x[i * 4 + 1] * v.y
               + x[i * 4 + 2] * v.z + x[i * 4 + 3] * v.w;
        }
        acc[e] = s;
    }

#pragma unroll
    for (int e = 0; e < N_EXP; ++e) {
        float a = acc[e];
#pragma unroll
        for (int off = 32; off > 0; off >>= 1) a += __shfl_xor(a, off);
        acc[e] = a;
    }

    if (lane == 0) {
        float lg[N_EXP];
#pragma unroll
        for (int e = 0; e < N_EXP; ++e) lg[e] = acc[e] + router_b[e];
        int e0 = 0;
#pragma unroll
        for (int e = 1; e < N_EXP; ++e) if (lg[e] > lg[e0]) e0 = e;
        int e1 = -1;
#pragma unroll
        for (int e = 0; e < N_EXP; ++e) {
            if (e == e0) continue;
            if (e1 < 0 || lg[e] > lg[e1]) e1 = e;
        }
        // exact collapsed weights: w0 = p0/(p0+p1) = sigmoid(l0-l1); eps terms < fp32 ulp
        float w0 = 1.f / (1.f + __expf(lg[e1] - lg[e0]));
        float w1 = 1.f - w0;
        int p0 = atomicAdd(&cnt[e0], 1);
        bucket[e0 * N_TOK + p0] = n * 2;
        int p1 = atomicAdd(&cnt[e1], 1);
        bucket[e1 * N_TOK + p1] = n * 2 + 1;
        w_arr[n * 2] = w0;
        w_arr[n * 2 + 1] = w1;
    }
}

// ---------------- K2: repack W[e][h][d] fp32 -> Bp[e][h>>3][d][h&7] bf16 ----------------
__global__ __launch_bounds__(256) void k_repack(
    const float* __restrict__ W, unsigned short* __restrict__ Bp)
{
    __shared__ __align__(16) unsigned short sm[8 * H_DIM];
    const int kg = blockIdx.x;   // 0..127
    const int e  = blockIdx.y;   // 0..7
    const int t  = threadIdx.x;
    const float* src = W + ((size_t)e * H_DIM + kg * 8) * H_DIM;
#pragma unroll
    for (int i = 0; i < 8; ++i) {
        int idx = (i * 256 + t) * 4;
        float4 v = *(const float4*)(src + idx);
        sm[idx + 0] = f2b(v.x); sm[idx + 1] = f2b(v.y);
        sm[idx + 2] = f2b(v.z); sm[idx + 3] = f2b(v.w);
    }
    __syncthreads();
    unsigned short* dst = Bp + (size_t)(e * 128 + kg) * H_DIM * 8;
#pragma unroll
    for (int i = 0; i < 4; ++i) {
        int d = i * 256 + t;   // consecutive t -> contiguous 16B stores
        unsigned short v[8];
#pragma unroll
        for (int j = 0; j < 8; ++j) v[j] = sm[j * H_DIM + d];
        *(uint4*)(dst + (size_t)d * 8) = *(uint4*)v;
    }
}

// ---------------- K3: grouped GEMM per expert, 128x128 tiles, bf16 MFMA ----------------
__global__ __launch_bounds__(256) void k_gemm(
    const unsigned short* __restrict__ tokb,
    const unsigned short* __restrict__ Bp,
    const int* __restrict__ cnt, const int* __restrict__ bucket,
    float* __restrict__ Y)
{
    const int nt = blockIdx.x;          // 0..7  (d tile)
    const int mt = blockIdx.y;          // 0..63 (row tile)
    const int e  = blockIdx.z;          // 0..7
    const int cnt_e = cnt[e];
    if (mt * 128 >= cnt_e) return;
    const int cnt_local = cnt_e - mt * 128;

    __shared__ __align__(16) unsigned short As[128][72]; // +8 pad: 144B stride
    __shared__ __align__(16) unsigned short Bsm[8 * 128 * 8]; // [kg][d][k&7] flat
    __shared__ int rows[128];

    const int t = threadIdx.x;
    if (t < 128)
        rows[t] = (t < cnt_local) ? bucket[e * N_TOK + mt * 128 + t] : -1;
    __syncthreads();

    const int r = t >> 1, half = t & 1;
    const int row_id = rows[r];
    const unsigned short* aptr =
        (row_id >= 0) ? tokb + (size_t)(row_id >> 1) * H_DIM + half * 32 : nullptr;

    const int d0 = nt * 128;
    // B staging: flat uint4 index u = i*256+t; kg = u>>7, d = u&127
    const int qd = t & 127;                 // d within chunk
    const int kg_hi = t >> 7;               // 0/1
    const unsigned short* bbase = Bp
        + ((size_t)(e * 128 + kg_hi) * H_DIM + d0 + qd) * 8;

    const int wv = t >> 6, lane = t & 63;
    const int w_row = wv >> 1, w_col = wv & 1;
    const int m_lane = lane & 15, quad = lane >> 4;

    floatx4 acc[4][4];
#pragma unroll
    for (int i = 0; i < 4; ++i)
#pragma unroll
        for (int j = 0; j < 4; ++j) acc[i][j] = (floatx4){0.f, 0.f, 0.f, 0.f};

    for (int kt = 0; kt < H_DIM / 64; ++kt) {
        // stage A (gathered bf16 rows), 64B per thread
        {
            unsigned short* dstA = &As[r][half * 32];
            if (aptr) {
                const unsigned short* s = aptr + kt * 64;
#pragma unroll
                for (int i = 0; i < 4; ++i)
                    *(uint4*)(dstA + i * 8) = *(const uint4*)(s + i * 8);
            } else {
                uint4 z = {0u, 0u, 0u, 0u};
#pragma unroll
                for (int i = 0; i < 4; ++i) *(uint4*)(dstA + i * 8) = z;
            }
        }
        // stage B: 4 uint4 per thread, flat (even LDS bank spread)
        {
            const unsigned short* s = bbase + (size_t)kt * 8 * H_DIM * 8;
#pragma unroll
            for (int i = 0; i < 4; ++i)
                *(uint4*)(&Bsm[(i * 256 + t) * 8]) = *(const uint4*)(s + (size_t)i * 2 * H_DIM * 8);
        }
        __syncthreads();

#pragma unroll
        for (int s = 0; s < 2; ++s) {
            bf16x8 a[4], b[4];
#pragma unroll
            for (int i = 0; i < 4; ++i)
                a[i] = *(const bf16x8*)&As[w_row * 64 + i * 16 + m_lane][s * 32 + quad * 8];
#pragma unroll
            for (int j = 0; j < 4; ++j)
                b[j] = *(const bf16x8*)&Bsm[((s * 4 + quad) * 128 + w_col * 64 + j * 16 + m_lane) * 8];
#pragma unroll
            for (int i = 0; i < 4; ++i)
#pragma unroll
                for (int j = 0; j < 4; ++j)
                    acc[i][j] = __builtin_amdgcn_mfma_f32_16x16x32_bf16(a[i], b[j], acc[i][j], 0, 0, 0);
        }
        __syncthreads();
    }

    // epilogue: C/D layout col=lane&15, row=quad*4+reg; Y fp32
#pragma unroll
    for (int i = 0; i < 4; ++i) {
        const int lr_base = w_row * 64 + i * 16 + quad * 4;
#pragma unroll
        for (int reg = 0; reg < 4; ++reg) {
            const int rid = rows[lr_base + reg];
            if (rid >= 0) {
#pragma unroll
                for (int j = 0; j < 4; ++j) {
                    const int d = d0 + w_col * 64 + j * 16 + m_lane;
                    Y[(size_t)rid * H_DIM + d] = acc[i][j][reg];
                }
            }
        }
    }
}

// ---------------- K4: combine out[n] = w0*Y[2n] + w1*Y[2n+1] (fp32) ----------------
__global__ __launch_bounds__(256) void k_combine(
    const float* __restrict__ Y, const float* __restrict__ w_arr,
    float* __restrict__ out)
{
    const int g = blockIdx.x * 256 + threadIdx.x;  // 2,097,152 threads, float4 each
    const int n = g >> 8;
    const int c = g & 255;
    const float4* y0 = (const float4*)(Y + (size_t)(n * 2) * H_DIM) + c;
    const float4* y1 = (const float4*)(Y + (size_t)(n * 2 + 1) * H_DIM) + c;
    const float w0 = w_arr[n * 2], w1 = w_arr[n * 2 + 1];
    float4 a = *y0, b = *y1, r;
    r.x = w0 * a.x + w1 * b.x;
    r.y = w0 * a.y + w1 * b.y;
    r.z = w0 * a.z + w1 * b.z;
    r.w = w0 * a.w + w1 * b.w;
    *((float4*)(out + (size_t)n * H_DIM) + c) = r;
}

extern "C" void kernel_launch(void* const* d_in, const int* in_sizes, int n_in,
                              void* d_out, int out_size, void* d_ws, size_t ws_size,
                              hipStream_t stream)
{
    const float* tokens   = (const float*)d_in[0]; // fp32 [8192,1024]
    const float* router_w = (const float*)d_in[1]; // fp32 [8,1024]
    const float* router_b = (const float*)d_in[2]; // fp32 [8]
    const float* W        = (const float*)d_in[3]; // fp32 [8,1024,1024]
    float* out = (float*)d_out;                    // fp32 [8192,1024]

    char* ws = (char*)d_ws;
    int*   cnt    = (int*)(ws);                        // 32 B
    int*   bucket = (int*)(ws + 1024);                 // 256 KB
    float* w_arr  = (float*)(ws + 263168);             // 64 KB
    unsigned short* tokb = (unsigned short*)(ws + 331776);    // 16 MB bf16 tokens
    unsigned short* Bp   = (unsigned short*)(ws + 17108992);  // 16 MB packed bf16 W
    float* Y             = (float*)(ws + 33886208);           // 64 MB fp32 per-slot outputs
    // total ~96.3 MB

    hipMemsetAsync(cnt, 0, N_EXP * sizeof(int), stream);
    k_router <<<N_TOK / 4, 256, 0, stream>>>(tokens, router_w, router_b, cnt, bucket, w_arr, tokb);
    k_repack <<<dim3(128, 8), 256, 0, stream>>>(W, Bp);
    k_gemm   <<<dim3(8, 64, 8), 256, 0, stream>>>(tokb, Bp, cnt, bucket, Y);
    k_combine<<<N_TOK * (H_DIM / 4) / 256, 256, 0, stream>>>(Y, w_arr, out);
}

// Round 3
// 242.005 us; speedup vs baseline: 1.5439x; 1.5439x over previous
//
#include <hip/hip_runtime.h>
#include <stdint.h>

// Problem constants (B=4, S=2048, H=1024, E=8, TOP_K=2). All I/O fp32.
#define N_TOK 8192
#define H_DIM 1024
#define N_EXP 8

typedef __bf16 bf16x8 __attribute__((ext_vector_type(8)));
typedef float floatx4 __attribute__((ext_vector_type(4)));

static __device__ __forceinline__ unsigned short f2b(float f) {
    union { float f; unsigned int i; } v; v.f = f;
    unsigned int u = v.i;
    return (unsigned short)((u + 0x7FFFu + ((u >> 16) & 1u)) >> 16);
}

// ---------------- K1: router (1 wave per token, fp32, NO atomics) + tokens->bf16 ----------------
__global__ __launch_bounds__(256) void k_router(
    const float* __restrict__ tokens,
    const float* __restrict__ router_w,
    const float* __restrict__ router_b,
    int* __restrict__ sel, float* __restrict__ w_arr,
    unsigned short* __restrict__ tokb)
{
    const int wave = threadIdx.x >> 6;
    const int lane = threadIdx.x & 63;
    const int n = blockIdx.x * 4 + wave;

    // lane handles 16 contiguous h values
    const float* xp = tokens + (size_t)n * H_DIM + lane * 16;
    float x[16];
#pragma unroll
    for (int i = 0; i < 4; ++i) {
        float4 v = *(const float4*)(xp + i * 4);
        x[i * 4 + 0] = v.x; x[i * 4 + 1] = v.y; x[i * 4 + 2] = v.z; x[i * 4 + 3] = v.w;
    }

    // emit bf16 copy of the token row (coalesced 32 B/lane)
    {
        unsigned short xb[16];
#pragma unroll
        for (int j = 0; j < 16; ++j) xb[j] = f2b(x[j]);
        unsigned short* dp = tokb + (size_t)n * H_DIM + lane * 16;
        *(uint4*)(dp)     = *(uint4*)(xb);
        *(uint4*)(dp + 8) = *(uint4*)(xb + 8);
    }

    float acc[N_EXP];
#pragma unroll
    for (int e = 0; e < N_EXP; ++e) {
        const float* wp = router_w + e * H_DIM + lane * 16;
        float s = 0.f;
#pragma unroll
        for (int i = 0; i < 4; ++i) {
            float4 v = *(const float4*)(wp + i * 4);
            s += x[i * 4 + 0] * v.x + x[i * 4 + 1] * v.y
               + x[i * 4 + 2] * v.z + x[i * 4 + 3] * v.w;
        }
        acc[e] = s;
    }

#pragma unroll
    for (int e = 0; e < N_EXP; ++e) {
        float a = acc[e];
#pragma unroll
        for (int off = 32; off > 0; off >>= 1) a += __shfl_xor(a, off);
        acc[e] = a;
    }

    if (lane == 0) {
        float lg[N_EXP];
#pragma unroll
        for (int e = 0; e < N_EXP; ++e) lg[e] = acc[e] + router_b[e];
        int e0 = 0;
#pragma unroll
        for (int e = 1; e < N_EXP; ++e) if (lg[e] > lg[e0]) e0 = e;
        int e1 = -1;
#pragma unroll
        for (int e = 0; e < N_EXP; ++e) {
            if (e == e0) continue;
            if (e1 < 0 || lg[e] > lg[e1]) e1 = e;
        }
        // exact collapsed weights: w0 = p0/(p0+p1) = sigmoid(l0-l1); eps terms < fp32 ulp
        float w0 = 1.f / (1.f + __expf(lg[e1] - lg[e0]));
        float w1 = 1.f - w0;
        sel[n] = e0 | (e1 << 4);
        w_arr[n * 2] = w0;
        w_arr[n * 2 + 1] = w1;
    }
}

// ---------------- K1b: single-block counting sort (deterministic, atomic-free) ----------------
__global__ __launch_bounds__(256) void k_scan(
    const int* __restrict__ sel, int* __restrict__ cnt, int* __restrict__ bucket)
{
    __shared__ int hist[256][8];
    const int t = threadIdx.x;
    const int base_n = t * 32;
    int h[8] = {0, 0, 0, 0, 0, 0, 0, 0};
    int sl[32];
#pragma unroll
    for (int i = 0; i < 32; ++i) {
        int s = sel[base_n + i];
        sl[i] = s;
        h[s & 15]++;
        h[(s >> 4) & 15]++;
    }
#pragma unroll
    for (int e = 0; e < 8; ++e) hist[t][e] = h[e];
    __syncthreads();
    // Hillis-Steele inclusive scan over the 256 threads (8-vector per thread)
    for (int off = 1; off < 256; off <<= 1) {
        int v[8];
        if (t >= off) {
#pragma unroll
            for (int e = 0; e < 8; ++e) v[e] = hist[t - off][e];
        }
        __syncthreads();
        if (t >= off) {
#pragma unroll
            for (int e = 0; e < 8; ++e) hist[t][e] += v[e];
        }
        __syncthreads();
    }
    int pos[8];
#pragma unroll
    for (int e = 0; e < 8; ++e) pos[e] = (t > 0) ? hist[t - 1][e] : 0;
    if (t == 255) {
#pragma unroll
        for (int e = 0; e < 8; ++e) cnt[e] = hist[255][e];
    }
#pragma unroll
    for (int i = 0; i < 32; ++i) {
        int s = sl[i];
        int e0 = s & 15, e1 = (s >> 4) & 15;
        int n = base_n + i;
        bucket[e0 * N_TOK + pos[e0]++] = n * 2;
        bucket[e1 * N_TOK + pos[e1]++] = n * 2 + 1;
    }
}

// ---------------- K2: repack W[e][h][d] fp32 -> Bp[e][h>>3][d][h&7] bf16 ----------------
__global__ __launch_bounds__(256) void k_repack(
    const float* __restrict__ W, unsigned short* __restrict__ Bp)
{
    __shared__ __align__(16) unsigned short sm[8 * H_DIM];
    const int kg = blockIdx.x;   // 0..127
    const int e  = blockIdx.y;   // 0..7
    const int t  = threadIdx.x;
    const float* src = W + ((size_t)e * H_DIM + kg * 8) * H_DIM;
#pragma unroll
    for (int i = 0; i < 8; ++i) {
        int idx = (i * 256 + t) * 4;
        float4 v = *(const float4*)(src + idx);
        sm[idx + 0] = f2b(v.x); sm[idx + 1] = f2b(v.y);
        sm[idx + 2] = f2b(v.z); sm[idx + 3] = f2b(v.w);
    }
    __syncthreads();
    unsigned short* dst = Bp + (size_t)(e * 128 + kg) * H_DIM * 8;
#pragma unroll
    for (int i = 0; i < 4; ++i) {
        int d = i * 256 + t;   // consecutive t -> contiguous 16B stores
        unsigned short v[8];
#pragma unroll
        for (int j = 0; j < 8; ++j) v[j] = sm[j * H_DIM + d];
        *(uint4*)(dst + (size_t)d * 8) = *(uint4*)v;
    }
}

// ---------------- K3: grouped GEMM per expert + fused weighted combine ----------------
__global__ __launch_bounds__(256) void k_gemm(
    const unsigned short* __restrict__ tokb,
    const unsigned short* __restrict__ Bp,
    const int* __restrict__ cnt, const int* __restrict__ bucket,
    const float* __restrict__ w_arr,
    float* __restrict__ out)
{
    const int nt = blockIdx.x;          // 0..7  (d tile)
    const int mt = blockIdx.y;          // 0..63 (row tile)
    const int e  = blockIdx.z;          // 0..7
    const int cnt_e = cnt[e];
    if (mt * 128 >= cnt_e) return;
    const int cnt_local = cnt_e - mt * 128;

    __shared__ __align__(16) unsigned short As[128][72]; // +8 pad: 144B stride
    __shared__ __align__(16) unsigned short Bsm[8 * 128 * 8]; // [kg][d][k&7] flat
    __shared__ int rows[128];
    __shared__ float wrow[128];

    const int t = threadIdx.x;
    if (t < 128) {
        int rid = (t < cnt_local) ? bucket[e * N_TOK + mt * 128 + t] : -1;
        rows[t] = rid;
        wrow[t] = (rid >= 0) ? w_arr[rid] : 0.f;
    }
    __syncthreads();

    const int r = t >> 1, half = t & 1;
    const int row_id = rows[r];
    const unsigned short* aptr =
        (row_id >= 0) ? tokb + (size_t)(row_id >> 1) * H_DIM + half * 32 : nullptr;

    const int d0 = nt * 128;
    // B staging: flat uint4 index u = i*256+t; kg = u>>7, d = u&127
    const int qd = t & 127;
    const int kg_hi = t >> 7;
    const unsigned short* bbase = Bp
        + ((size_t)(e * 128 + kg_hi) * H_DIM + d0 + qd) * 8;

    const int wv = t >> 6, lane = t & 63;
    const int w_row = wv >> 1, w_col = wv & 1;
    const int m_lane = lane & 15, quad = lane >> 4;

    floatx4 acc[4][4];
#pragma unroll
    for (int i = 0; i < 4; ++i)
#pragma unroll
        for (int j = 0; j < 4; ++j) acc[i][j] = (floatx4){0.f, 0.f, 0.f, 0.f};

    for (int kt = 0; kt < H_DIM / 64; ++kt) {
        // stage A (gathered bf16 rows), 64B per thread
        {
            unsigned short* dstA = &As[r][half * 32];
            if (aptr) {
                const unsigned short* s = aptr + kt * 64;
#pragma unroll
                for (int i = 0; i < 4; ++i)
                    *(uint4*)(dstA + i * 8) = *(const uint4*)(s + i * 8);
            } else {
                uint4 z = {0u, 0u, 0u, 0u};
#pragma unroll
                for (int i = 0; i < 4; ++i) *(uint4*)(dstA + i * 8) = z;
            }
        }
        // stage B: 4 uint4 per thread, flat (even LDS bank spread)
        {
            const unsigned short* s = bbase + (size_t)kt * 8 * H_DIM * 8;
#pragma unroll
            for (int i = 0; i < 4; ++i)
                *(uint4*)(&Bsm[(i * 256 + t) * 8]) = *(const uint4*)(s + (size_t)i * 2 * H_DIM * 8);
        }
        __syncthreads();

#pragma unroll
        for (int s = 0; s < 2; ++s) {
            bf16x8 a[4], b[4];
#pragma unroll
            for (int i = 0; i < 4; ++i)
                a[i] = *(const bf16x8*)&As[w_row * 64 + i * 16 + m_lane][s * 32 + quad * 8];
#pragma unroll
            for (int j = 0; j < 4; ++j)
                b[j] = *(const bf16x8*)&Bsm[((s * 4 + quad) * 128 + w_col * 64 + j * 16 + m_lane) * 8];
#pragma unroll
            for (int i = 0; i < 4; ++i)
#pragma unroll
                for (int j = 0; j < 4; ++j)
                    acc[i][j] = __builtin_amdgcn_mfma_f32_16x16x32_bf16(a[i], b[j], acc[i][j], 0, 0, 0);
        }
        __syncthreads();
    }

    // fused epilogue: out[tok] += w_slot * acc   (each dword has exactly 2 writers)
    // C/D layout: col=lane&15, row=quad*4+reg
#pragma unroll
    for (int i = 0; i < 4; ++i) {
        const int lr_base = w_row * 64 + i * 16 + quad * 4;
#pragma unroll
        for (int reg = 0; reg < 4; ++reg) {
            const int lr = lr_base + reg;
            const int rid = rows[lr];
            if (rid >= 0) {
                const float wgt = wrow[lr];
                float* op = out + (size_t)(rid >> 1) * H_DIM + d0 + w_col * 64 + m_lane;
#pragma unroll
                for (int j = 0; j < 4; ++j)
                    atomicAdd(op + j * 16, wgt * acc[i][j][reg]);
            }
        }
    }
}

extern "C" void kernel_launch(void* const* d_in, const int* in_sizes, int n_in,
                              void* d_out, int out_size, void* d_ws, size_t ws_size,
                              hipStream_t stream)
{
    const float* tokens   = (const float*)d_in[0]; // fp32 [8192,1024]
    const float* router_w = (const float*)d_in[1]; // fp32 [8,1024]
    const float* router_b = (const float*)d_in[2]; // fp32 [8]
    const float* W        = (const float*)d_in[3]; // fp32 [8,1024,1024]
    float* out = (float*)d_out;                    // fp32 [8192,1024]

    char* ws = (char*)d_ws;
    int*   cnt    = (int*)(ws);                        // 32 B
    int*   sel    = (int*)(ws + 1024);                 // 32 KB
    float* w_arr  = (float*)(ws + 34816);              // 64 KB
    int*   bucket = (int*)(ws + 100352);               // 256 KB
    unsigned short* tokb = (unsigned short*)(ws + 362496);    // 16 MB bf16 tokens
    unsigned short* Bp   = (unsigned short*)(ws + 17139712);  // 16 MB packed bf16 W
    // total ~33 MB

    hipMemsetAsync(out, 0, (size_t)out_size * sizeof(float), stream);
    k_router <<<N_TOK / 4, 256, 0, stream>>>(tokens, router_w, router_b, sel, w_arr, tokb);
    k_scan   <<<1, 256, 0, stream>>>(sel, cnt, bucket);
    k_repack <<<dim3(128, 8), 256, 0, stream>>>(W, Bp);
    k_gemm   <<<dim3(8, 64, 8), 256, 0, stream>>>(tokb, Bp, cnt, bucket, w_arr, out);
}

// Round 4
// 229.189 us; speedup vs baseline: 1.6302x; 1.0559x over previous
//
#include <hip/hip_runtime.h>
#include <stdint.h>

// Problem constants (B=4, S=2048, H=1024, E=8, TOP_K=2). All I/O fp32.
#define N_TOK 8192
#define H_DIM 1024
#define N_EXP 8

typedef __bf16 bf16x8 __attribute__((ext_vector_type(8)));
typedef float floatx4 __attribute__((ext_vector_type(4)));

typedef __attribute__((address_space(1))) void GV;
typedef __attribute__((address_space(3))) void LV;

static __device__ __forceinline__ unsigned short f2b(float f) {
    union { float f; unsigned int i; } v; v.f = f;
    unsigned int u = v.i;
    return (unsigned short)((u + 0x7FFFu + ((u >> 16) & 1u)) >> 16);
}

// ---------------- K1: router (1 wave per token, fp32, NO atomics) + tokens->bf16 ----------------
__global__ __launch_bounds__(256) void k_router(
    const float* __restrict__ tokens,
    const float* __restrict__ router_w,
    const float* __restrict__ router_b,
    int* __restrict__ sel, float* __restrict__ w_arr,
    unsigned short* __restrict__ tokb)
{
    const int wave = threadIdx.x >> 6;
    const int lane = threadIdx.x & 63;
    const int n = blockIdx.x * 4 + wave;

    const float* xp = tokens + (size_t)n * H_DIM + lane * 16;
    float x[16];
#pragma unroll
    for (int i = 0; i < 4; ++i) {
        float4 v = *(const float4*)(xp + i * 4);
        x[i * 4 + 0] = v.x; x[i * 4 + 1] = v.y; x[i * 4 + 2] = v.z; x[i * 4 + 3] = v.w;
    }

    {
        unsigned short xb[16];
#pragma unroll
        for (int j = 0; j < 16; ++j) xb[j] = f2b(x[j]);
        unsigned short* dp = tokb + (size_t)n * H_DIM + lane * 16;
        *(uint4*)(dp)     = *(uint4*)(xb);
        *(uint4*)(dp + 8) = *(uint4*)(xb + 8);
    }

    float acc[N_EXP];
#pragma unroll
    for (int e = 0; e < N_EXP; ++e) {
        const float* wp = router_w + e * H_DIM + lane * 16;
        float s = 0.f;
#pragma unroll
        for (int i = 0; i < 4; ++i) {
            float4 v = *(const float4*)(wp + i * 4);
            s += x[i * 4 + 0] * v.x + x[i * 4 + 1] * v.y
               + x[i * 4 + 2] * v.z + x[i * 4 + 3] * v.w;
        }
        acc[e] = s;
    }

#pragma unroll
    for (int e = 0; e < N_EXP; ++e) {
        float a = acc[e];
#pragma unroll
        for (int off = 32; off > 0; off >>= 1) a += __shfl_xor(a, off);
        acc[e] = a;
    }

    if (lane == 0) {
        float lg[N_EXP];
#pragma unroll
        for (int e = 0; e < N_EXP; ++e) lg[e] = acc[e] + router_b[e];
        int e0 = 0;
#pragma unroll
        for (int e = 1; e < N_EXP; ++e) if (lg[e] > lg[e0]) e0 = e;
        int e1 = -1;
#pragma unroll
        for (int e = 0; e < N_EXP; ++e) {
            if (e == e0) continue;
            if (e1 < 0 || lg[e] > lg[e1]) e1 = e;
        }
        float w0 = 1.f / (1.f + __expf(lg[e1] - lg[e0]));
        float w1 = 1.f - w0;
        sel[n] = e0 | (e1 << 4);
        w_arr[n * 2] = w0;
        w_arr[n * 2 + 1] = w1;
    }
}

// ---------------- K1b: counting sort, one block per expert (deterministic) ----------------
__global__ __launch_bounds__(256) void k_scan(
    const int* __restrict__ sel, int* __restrict__ cnt, int* __restrict__ bucket)
{
    __shared__ int ssel[N_TOK + N_TOK / 32];   // padded: idx n -> n + (n>>5)
    __shared__ int sc[256];
    const int e = blockIdx.x;
    const int t = threadIdx.x;
#pragma unroll
    for (int i = 0; i < 32; ++i) {
        int n = i * 256 + t;
        ssel[n + (n >> 5)] = sel[n];
    }
    __syncthreads();
    const int base = t * 32;
    int c = 0;
#pragma unroll
    for (int i = 0; i < 32; ++i) {
        int n = base + i;
        int s = ssel[n + (n >> 5)];
        c += ((s & 15) == e) + (((s >> 4) & 15) == e);
    }
    sc[t] = c;
    __syncthreads();
    for (int off = 1; off < 256; off <<= 1) {
        int v = (t >= off) ? sc[t - off] : 0;
        __syncthreads();
        sc[t] += v;
        __syncthreads();
    }
    int pos = sc[t] - c;   // exclusive prefix
    if (t == 255) cnt[e] = sc[255];
#pragma unroll
    for (int i = 0; i < 32; ++i) {
        int n = base + i;
        int s = ssel[n + (n >> 5)];
        if ((s & 15) == e)        bucket[e * N_TOK + pos++] = 2 * n;
        if (((s >> 4) & 15) == e) bucket[e * N_TOK + pos++] = 2 * n + 1;
    }
}

// ---------------- K2: repack W[e][h][d] fp32 -> Bp[e][h>>3][d][h&7] bf16 ----------------
__global__ __launch_bounds__(256) void k_repack(
    const float* __restrict__ W, unsigned short* __restrict__ Bp)
{
    __shared__ __align__(16) unsigned short sm[8 * H_DIM];
    const int kg = blockIdx.x;   // 0..127
    const int e  = blockIdx.y;   // 0..7
    const int t  = threadIdx.x;
    const float* src = W + ((size_t)e * H_DIM + kg * 8) * H_DIM;
#pragma unroll
    for (int i = 0; i < 8; ++i) {
        int idx = (i * 256 + t) * 4;
        float4 v = *(const float4*)(src + idx);
        sm[idx + 0] = f2b(v.x); sm[idx + 1] = f2b(v.y);
        sm[idx + 2] = f2b(v.z); sm[idx + 3] = f2b(v.w);
    }
    __syncthreads();
    unsigned short* dst = Bp + (size_t)(e * 128 + kg) * H_DIM * 8;
#pragma unroll
    for (int i = 0; i < 4; ++i) {
        int d = i * 256 + t;
        unsigned short v[8];
#pragma unroll
        for (int j = 0; j < 8; ++j) v[j] = sm[j * H_DIM + d];
        *(uint4*)(dst + (size_t)d * 8) = *(uint4*)v;
    }
}

// ---------------- K3: grouped GEMM + fused weighted combine (global_load_lds staging) ----------------
__global__ __launch_bounds__(256) void k_gemm(
    const unsigned short* __restrict__ tokb,
    const unsigned short* __restrict__ Bp,
    const int* __restrict__ cnt, const int* __restrict__ bucket,
    const float* __restrict__ w_arr,
    float* __restrict__ out)
{
    const int nt = blockIdx.x;          // 0..7  (d tile)
    const int mt = blockIdx.y;          // 0..63 (row tile)
    const int e  = blockIdx.z;          // 0..7
    const int cnt_e = cnt[e];
    if (mt * 128 >= cnt_e) return;
    const int cnt_local = cnt_e - mt * 128;

    // As: flat [row][64], XOR-swizzled: (row, part) lives at row*64 + (part^(row&7))*8
    __shared__ __align__(16) unsigned short Asm[128 * 64];
    __shared__ __align__(16) unsigned short Bsm[8 * 128 * 8];  // chunk (kg,d) at (kg*128+d)*8
    __shared__ int rows[128];
    __shared__ float wrow[128];

    const int t = threadIdx.x;
    if (t < 128) {
        int rid = (t < cnt_local) ? bucket[e * N_TOK + mt * 128 + t] : -1;
        rows[t] = rid;
        wrow[t] = (rid >= 0) ? w_arr[rid] : 0.f;
    }
    __syncthreads();

    const int wv = t >> 6, lane = t & 63;
    const int d0 = nt * 128;

    // A staging source: instr i, lane l covers LDS chunk c = i*256+wv*64+l
    // -> row r = c>>3 = i*32+wv*8+(l>>3), swizzled slot l&7 holds global part p=(l&7)^(r&7)
    const int p_sw = (lane & 7) ^ ((lane >> 3) & 7);
    const unsigned short* aptr[4];
#pragma unroll
    for (int i = 0; i < 4; ++i) {
        int r = i * 32 + wv * 8 + (lane >> 3);
        int rid = rows[r];
        int tok = (rid >= 0) ? (rid >> 1) : 0;   // inactive rows read token 0; masked in epilogue
        aptr[i] = tokb + (size_t)tok * H_DIM + p_sw * 8;
    }
    // B staging source: chunk c = i*256+t -> kg' = c>>7 = i*2+(t>>7), d = t&127
    const unsigned short* bbase = Bp
        + ((size_t)(e * 128 + (t >> 7)) * H_DIM + d0 + (t & 127)) * 8;

    const int w_row = wv >> 1, w_col = wv & 1;
    const int m_lane = lane & 15, quad = lane >> 4;
    const int r7 = m_lane & 7;

    floatx4 acc[4][4];
#pragma unroll
    for (int i = 0; i < 4; ++i)
#pragma unroll
        for (int j = 0; j < 4; ++j) acc[i][j] = (floatx4){0.f, 0.f, 0.f, 0.f};

    for (int kt = 0; kt < H_DIM / 64; ++kt) {
#pragma unroll
        for (int i = 0; i < 4; ++i) {
            __builtin_amdgcn_global_load_lds(
                (GV*)(aptr[i] + kt * 64),
                (LV*)(&Asm[i * 2048 + wv * 512]), 16, 0, 0);
            __builtin_amdgcn_global_load_lds(
                (GV*)(bbase + (size_t)i * 16384 + (size_t)kt * 65536),
                (LV*)(&Bsm[i * 2048 + wv * 512]), 16, 0, 0);
        }
        __syncthreads();

#pragma unroll
        for (int s = 0; s < 2; ++s) {
            bf16x8 a[4], b[4];
#pragma unroll
            for (int i = 0; i < 4; ++i) {
                int row = w_row * 64 + i * 16 + m_lane;
                a[i] = *(const bf16x8*)&Asm[row * 64 + ((s * 4 + quad) ^ r7) * 8];
            }
#pragma unroll
            for (int j = 0; j < 4; ++j)
                b[j] = *(const bf16x8*)&Bsm[((s * 4 + quad) * 128 + w_col * 64 + j * 16 + m_lane) * 8];
#pragma unroll
            for (int i = 0; i < 4; ++i)
#pragma unroll
                for (int j = 0; j < 4; ++j)
                    acc[i][j] = __builtin_amdgcn_mfma_f32_16x16x32_bf16(a[i], b[j], acc[i][j], 0, 0, 0);
        }
        __syncthreads();
    }

    // fused epilogue: out[tok] += w_slot * acc   (each dword has exactly 2 writers)
#pragma unroll
    for (int i = 0; i < 4; ++i) {
        const int lr_base = w_row * 64 + i * 16 + quad * 4;
#pragma unroll
        for (int reg = 0; reg < 4; ++reg) {
            const int lr = lr_base + reg;
            const int rid = rows[lr];
            if (rid >= 0) {
                const float wgt = wrow[lr];
                float* op = out + (size_t)(rid >> 1) * H_DIM + d0 + w_col * 64 + m_lane;
#pragma unroll
                for (int j = 0; j < 4; ++j)
                    atomicAdd(op + j * 16, wgt * acc[i][j][reg]);
            }
        }
    }
}

extern "C" void kernel_launch(void* const* d_in, const int* in_sizes, int n_in,
                              void* d_out, int out_size, void* d_ws, size_t ws_size,
                              hipStream_t stream)
{
    const float* tokens   = (const float*)d_in[0]; // fp32 [8192,1024]
    const float* router_w = (const float*)d_in[1]; // fp32 [8,1024]
    const float* router_b = (const float*)d_in[2]; // fp32 [8]
    const float* W        = (const float*)d_in[3]; // fp32 [8,1024,1024]
    float* out = (float*)d_out;                    // fp32 [8192,1024]

    char* ws = (char*)d_ws;
    int*   cnt    = (int*)(ws);                        // 32 B
    int*   sel    = (int*)(ws + 1024);                 // 32 KB
    float* w_arr  = (float*)(ws + 34816);              // 64 KB
    int*   bucket = (int*)(ws + 100352);               // 256 KB
    unsigned short* tokb = (unsigned short*)(ws + 362496);    // 16 MB bf16 tokens
    unsigned short* Bp   = (unsigned short*)(ws + 17139712);  // 16 MB packed bf16 W

    hipMemsetAsync(out, 0, (size_t)out_size * sizeof(float), stream);
    k_router <<<N_TOK / 4, 256, 0, stream>>>(tokens, router_w, router_b, sel, w_arr, tokb);
    k_scan   <<<N_EXP, 256, 0, stream>>>(sel, cnt, bucket);
    k_repack <<<dim3(128, 8), 256, 0, stream>>>(W, Bp);
    k_gemm   <<<dim3(8, 64, 8), 256, 0, stream>>>(tokb, Bp, cnt, bucket, w_arr, out);
}

// Round 5
// 221.535 us; speedup vs baseline: 1.6865x; 1.0346x over previous
//
#include <hip/hip_runtime.h>
#include <stdint.h>

// Problem constants (B=4, S=2048, H=1024, E=8, TOP_K=2). All I/O fp32.
#define N_TOK 8192
#define H_DIM 1024
#define N_EXP 8
#define MAX_TILES 136   // sum over experts of ceil(cnt_e/128) <= 128 + 7, padded

typedef __bf16 bf16x8 __attribute__((ext_vector_type(8)));
typedef float floatx4 __attribute__((ext_vector_type(4)));

typedef __attribute__((address_space(1))) void GV;
typedef __attribute__((address_space(3))) void LV;

static __device__ __forceinline__ unsigned short f2b(float f) {
    union { float f; unsigned int i; } v; v.f = f;
    unsigned int u = v.i;
    return (unsigned short)((u + 0x7FFFu + ((u >> 16) & 1u)) >> 16);
}

// ---------------- K1: fused router (blocks 0..2047) + W repack (blocks 2048..3071) ----------------
__global__ __launch_bounds__(256) void k_front(
    const float* __restrict__ tokens,
    const float* __restrict__ router_w,
    const float* __restrict__ router_b,
    const float* __restrict__ W,
    int* __restrict__ sel, float* __restrict__ w_arr,
    unsigned short* __restrict__ tokb,
    unsigned short* __restrict__ Bp)
{
    __shared__ __align__(16) unsigned short sm[8 * H_DIM];
    const int t = threadIdx.x;

    if (blockIdx.x >= 2048) {
        // ---- repack W[e][h][d] fp32 -> Bp[e][h>>3][d][h&7] bf16 ----
        const int idx = blockIdx.x - 2048;   // 0..1023
        const int kg = idx & 127;
        const int e  = idx >> 7;
        const float* src = W + ((size_t)e * H_DIM + kg * 8) * H_DIM;
#pragma unroll
        for (int i = 0; i < 8; ++i) {
            int p = (i * 256 + t) * 4;
            float4 v = *(const float4*)(src + p);
            sm[p + 0] = f2b(v.x); sm[p + 1] = f2b(v.y);
            sm[p + 2] = f2b(v.z); sm[p + 3] = f2b(v.w);
        }
        __syncthreads();
        unsigned short* dst = Bp + (size_t)(e * 128 + kg) * H_DIM * 8;
#pragma unroll
        for (int i = 0; i < 4; ++i) {
            int d = i * 256 + t;
            unsigned short v[8];
#pragma unroll
            for (int j = 0; j < 8; ++j) v[j] = sm[j * H_DIM + d];
            *(uint4*)(dst + (size_t)d * 8) = *(uint4*)v;
        }
        return;
    }

    // ---- router: 1 wave per token, fp32, no atomics; also emit bf16 tokens ----
    const int wave = t >> 6;
    const int lane = t & 63;
    const int n = blockIdx.x * 4 + wave;

    const float* xp = tokens + (size_t)n * H_DIM + lane * 16;
    float x[16];
#pragma unroll
    for (int i = 0; i < 4; ++i) {
        float4 v = *(const float4*)(xp + i * 4);
        x[i * 4 + 0] = v.x; x[i * 4 + 1] = v.y; x[i * 4 + 2] = v.z; x[i * 4 + 3] = v.w;
    }

    {
        unsigned short xb[16];
#pragma unroll
        for (int j = 0; j < 16; ++j) xb[j] = f2b(x[j]);
        unsigned short* dp = tokb + (size_t)n * H_DIM + lane * 16;
        *(uint4*)(dp)     = *(uint4*)(xb);
        *(uint4*)(dp + 8) = *(uint4*)(xb + 8);
    }

    float acc[N_EXP];
#pragma unroll
    for (int e = 0; e < N_EXP; ++e) {
        const float* wp = router_w + e * H_DIM + lane * 16;
        float s = 0.f;
#pragma unroll
        for (int i = 0; i < 4; ++i) {
            float4 v = *(const float4*)(wp + i * 4);
            s += x[i * 4 + 0] * v.x + x[i * 4 + 1] * v.y
               + x[i * 4 + 2] * v.z + x[i * 4 + 3] * v.w;
        }
        acc[e] = s;
    }

#pragma unroll
    for (int e = 0; e < N_EXP; ++e) {
        float a = acc[e];
#pragma unroll
        for (int off = 32; off > 0; off >>= 1) a += __shfl_xor(a, off);
        acc[e] = a;
    }

    if (lane == 0) {
        float lg[N_EXP];
#pragma unroll
        for (int e = 0; e < N_EXP; ++e) lg[e] = acc[e] + router_b[e];
        int e0 = 0;
#pragma unroll
        for (int e = 1; e < N_EXP; ++e) if (lg[e] > lg[e0]) e0 = e;
        int e1 = -1;
#pragma unroll
        for (int e = 0; e < N_EXP; ++e) {
            if (e == e0) continue;
            if (e1 < 0 || lg[e] > lg[e1]) e1 = e;
        }
        // collapsed weights: w0 = p0/(p0+p1) = sigmoid(l0-l1); eps terms < fp32 ulp
        float w0 = 1.f / (1.f + __expf(lg[e1] - lg[e0]));
        float w1 = 1.f - w0;
        sel[n] = e0 | (e1 << 4);
        w_arr[n * 2] = w0;
        w_arr[n * 2 + 1] = w1;
    }
}

// ---------------- K1b: counting sort, one block per expert (deterministic) ----------------
__global__ __launch_bounds__(256) void k_scan(
    const int* __restrict__ sel, int* __restrict__ cnt, int* __restrict__ bucket)
{
    __shared__ int ssel[N_TOK + N_TOK / 32];   // padded: idx n -> n + (n>>5)
    __shared__ int sc[256];
    const int e = blockIdx.x;
    const int t = threadIdx.x;
#pragma unroll
    for (int i = 0; i < 32; ++i) {
        int n = i * 256 + t;
        ssel[n + (n >> 5)] = sel[n];
    }
    __syncthreads();
    const int base = t * 32;
    int c = 0;
#pragma unroll
    for (int i = 0; i < 32; ++i) {
        int n = base + i;
        int s = ssel[n + (n >> 5)];
        c += ((s & 15) == e) + (((s >> 4) & 15) == e);
    }
    sc[t] = c;
    __syncthreads();
    for (int off = 1; off < 256; off <<= 1) {
        int v = (t >= off) ? sc[t - off] : 0;
        __syncthreads();
        sc[t] += v;
        __syncthreads();
    }
    int pos = sc[t] - c;   // exclusive prefix
    if (t == 255) cnt[e] = sc[255];
#pragma unroll
    for (int i = 0; i < 32; ++i) {
        int n = base + i;
        int s = ssel[n + (n >> 5)];
        if ((s & 15) == e)        bucket[e * N_TOK + pos++] = 2 * n;
        if (((s >> 4) & 15) == e) bucket[e * N_TOK + pos++] = 2 * n + 1;
    }
}

// ---------------- K3: grouped GEMM + fused weighted combine (compacted flat grid) ----------------
__global__ __launch_bounds__(256, 4) void k_gemm(
    const unsigned short* __restrict__ tokb,
    const unsigned short* __restrict__ Bp,
    const int* __restrict__ cnt, const int* __restrict__ bucket,
    const float* __restrict__ w_arr,
    float* __restrict__ out)
{
    // flat grid: bid = tile*8 + nt; decode (e, mt) from cnt[] prefix
    const int nt = blockIdx.x & 7;
    const int tile = blockIdx.x >> 3;
    int base = 0, e = 0, mt = -1;
#pragma unroll
    for (int ee = 0; ee < 8; ++ee) {
        int te = (cnt[ee] + 127) >> 7;
        if (tile >= base && tile < base + te) { e = ee; mt = tile - base; }
        base += te;
    }
    if (mt < 0) return;
    const int cnt_local = cnt[e] - mt * 128;   // >128 means full tile

    // As: flat [row][64], XOR-swizzled: (row, part) lives at row*64 + (part^(row&7))*8
    __shared__ __align__(16) unsigned short Asm[128 * 64];
    __shared__ __align__(16) unsigned short Bsm[8 * 128 * 8];  // chunk (kg,d) at (kg*128+d)*8
    __shared__ int rows[128];
    __shared__ float wrow[128];

    const int t = threadIdx.x;
    if (t < 128) {
        int rid = (t < cnt_local) ? bucket[e * N_TOK + mt * 128 + t] : -1;
        rows[t] = rid;
        wrow[t] = (rid >= 0) ? w_arr[rid] : 0.f;
    }
    __syncthreads();

    const int wv = t >> 6, lane = t & 63;
    const int d0 = nt * 128;

    // A staging: instr i, lane l covers LDS chunk c = i*256+wv*64+l
    // -> row r = c>>3 = i*32+wv*8+(l>>3), swizzled slot l&7 holds global part p=(l&7)^(r&7)
    const int p_sw = (lane & 7) ^ ((lane >> 3) & 7);
    const unsigned short* aptr[4];
#pragma unroll
    for (int i = 0; i < 4; ++i) {
        int r = i * 32 + wv * 8 + (lane >> 3);
        int rid = rows[r];
        int tok = (rid >= 0) ? (rid >> 1) : 0;   // inactive rows read token 0; masked in epilogue
        aptr[i] = tokb + (size_t)tok * H_DIM + p_sw * 8;
    }
    // B staging: chunk c = i*256+t -> kg' = c>>7 = i*2+(t>>7), d = t&127
    const unsigned short* bbase = Bp
        + ((size_t)(e * 128 + (t >> 7)) * H_DIM + d0 + (t & 127)) * 8;

    const int w_row = wv >> 1, w_col = wv & 1;
    const int m_lane = lane & 15, quad = lane >> 4;
    const int r7 = m_lane & 7;

    floatx4 acc[4][4];
#pragma unroll
    for (int i = 0; i < 4; ++i)
#pragma unroll
        for (int j = 0; j < 4; ++j) acc[i][j] = (floatx4){0.f, 0.f, 0.f, 0.f};

    for (int kt = 0; kt < H_DIM / 64; ++kt) {
#pragma unroll
        for (int i = 0; i < 4; ++i) {
            __builtin_amdgcn_global_load_lds(
                (GV*)(aptr[i] + kt * 64),
                (LV*)(&Asm[i * 2048 + wv * 512]), 16, 0, 0);
            __builtin_amdgcn_global_load_lds(
                (GV*)(bbase + (size_t)i * 16384 + (size_t)kt * 65536),
                (LV*)(&Bsm[i * 2048 + wv * 512]), 16, 0, 0);
        }
        __syncthreads();

#pragma unroll
        for (int s = 0; s < 2; ++s) {
            bf16x8 a[4], b[4];
#pragma unroll
            for (int i = 0; i < 4; ++i) {
                int row = w_row * 64 + i * 16 + m_lane;
                a[i] = *(const bf16x8*)&Asm[row * 64 + ((s * 4 + quad) ^ r7) * 8];
            }
#pragma unroll
            for (int j = 0; j < 4; ++j)
                b[j] = *(const bf16x8*)&Bsm[((s * 4 + quad) * 128 + w_col * 64 + j * 16 + m_lane) * 8];
#pragma unroll
            for (int i = 0; i < 4; ++i)
#pragma unroll
                for (int j = 0; j < 4; ++j)
                    acc[i][j] = __builtin_amdgcn_mfma_f32_16x16x32_bf16(a[i], b[j], acc[i][j], 0, 0, 0);
        }
        __syncthreads();
    }

    // fused epilogue: out[tok] += w_slot * acc   (each dword has exactly 2 writers)
#pragma unroll
    for (int i = 0; i < 4; ++i) {
        const int lr_base = w_row * 64 + i * 16 + quad * 4;
#pragma unroll
        for (int reg = 0; reg < 4; ++reg) {
            const int lr = lr_base + reg;
            const int rid = rows[lr];
            if (rid >= 0) {
                const float wgt = wrow[lr];
                float* op = out + (size_t)(rid >> 1) * H_DIM + d0 + w_col * 64 + m_lane;
#pragma unroll
                for (int j = 0; j < 4; ++j)
                    atomicAdd(op + j * 16, wgt * acc[i][j][reg]);
            }
        }
    }
}

extern "C" void kernel_launch(void* const* d_in, const int* in_sizes, int n_in,
                              void* d_out, int out_size, void* d_ws, size_t ws_size,
                              hipStream_t stream)
{
    const float* tokens   = (const float*)d_in[0]; // fp32 [8192,1024]
    const float* router_w = (const float*)d_in[1]; // fp32 [8,1024]
    const float* router_b = (const float*)d_in[2]; // fp32 [8]
    const float* W        = (const float*)d_in[3]; // fp32 [8,1024,1024]
    float* out = (float*)d_out;                    // fp32 [8192,1024]

    char* ws = (char*)d_ws;
    int*   cnt    = (int*)(ws);                        // 32 B
    int*   sel    = (int*)(ws + 1024);                 // 32 KB
    float* w_arr  = (float*)(ws + 34816);              // 64 KB
    int*   bucket = (int*)(ws + 100352);               // 256 KB
    unsigned short* tokb = (unsigned short*)(ws + 362496);    // 16 MB bf16 tokens
    unsigned short* Bp   = (unsigned short*)(ws + 17139712);  // 16 MB packed bf16 W

    hipMemsetAsync(out, 0, (size_t)out_size * sizeof(float), stream);
    k_front<<<2048 + 1024, 256, 0, stream>>>(tokens, router_w, router_b, W,
                                             sel, w_arr, tokb, Bp);
    k_scan <<<N_EXP, 256, 0, stream>>>(sel, cnt, bucket);
    k_gemm <<<MAX_TILES * 8, 256, 0, stream>>>(tokb, Bp, cnt, bucket, w_arr, out);
}

// Round 7
// 194.786 us; speedup vs baseline: 1.9181x; 1.1373x over previous
//
#include <hip/hip_runtime.h>
#include <stdint.h>

// Problem constants (B=4, S=2048, H=1024, E=8, TOP_K=2). All I/O fp32.
#define N_TOK 8192
#define H_DIM 1024
#define N_EXP 8
#define MAX_TILES 136   // sum over experts of ceil(cnt_e/128) <= 128 + 7, padded

typedef __bf16 bf16x8 __attribute__((ext_vector_type(8)));
typedef float floatx4 __attribute__((ext_vector_type(4)));

typedef __attribute__((address_space(1))) void GV;
typedef __attribute__((address_space(3))) void LV;

static __device__ __forceinline__ unsigned short f2b(float f) {
    union { float f; unsigned int i; } v; v.f = f;
    unsigned int u = v.i;
    return (unsigned short)((u + 0x7FFFu + ((u >> 16) & 1u)) >> 16);
}
static __device__ __forceinline__ float b2f(unsigned short u) {
    union { unsigned int i; float f; } v; v.i = ((unsigned int)u) << 16; return v.f;
}

// ---------------- K1: fused router (blocks 0..2047) + W repack (blocks 2048..3071) ----------------
__global__ __launch_bounds__(256) void k_front(
    const float* __restrict__ tokens,
    const float* __restrict__ router_w,
    const float* __restrict__ router_b,
    const float* __restrict__ W,
    int* __restrict__ sel, float* __restrict__ w_arr,
    unsigned short* __restrict__ tokb,
    unsigned short* __restrict__ Bp)
{
    const int t = threadIdx.x;

    if (blockIdx.x >= 2048) {
        // ---- repack W[e][h][d] fp32 -> Bp[e][h>>3][d][h&7] bf16 (no LDS) ----
        const int idx = blockIdx.x - 2048;   // 0..1023
        const int kg = idx & 127;
        const int e  = idx >> 7;
        const int d  = t * 4;                // thread owns 4 consecutive d
        const float* src = W + ((size_t)e * H_DIM + kg * 8) * H_DIM + d;
        float col[8][4];
#pragma unroll
        for (int j = 0; j < 8; ++j) {
            float4 v = *(const float4*)(src + (size_t)j * H_DIM);
            col[j][0] = v.x; col[j][1] = v.y; col[j][2] = v.z; col[j][3] = v.w;
        }
        unsigned short* dst = Bp + ((size_t)(e * 128 + kg) * H_DIM + d) * 8;
#pragma unroll
        for (int k = 0; k < 4; ++k) {
            unsigned short v[8];
#pragma unroll
            for (int j = 0; j < 8; ++j) v[j] = f2b(col[j][k]);
            *(uint4*)(dst + (size_t)k * 8) = *(uint4*)v;
        }
        return;
    }

    // ---- router: 1 wave per token, fp32, no atomics; also emit bf16 tokens ----
    const int wave = t >> 6;
    const int lane = t & 63;
    const int n = blockIdx.x * 4 + wave;

    const float* xp = tokens + (size_t)n * H_DIM + lane * 16;
    float x[16];
#pragma unroll
    for (int i = 0; i < 4; ++i) {
        float4 v = *(const float4*)(xp + i * 4);
        x[i * 4 + 0] = v.x; x[i * 4 + 1] = v.y; x[i * 4 + 2] = v.z; x[i * 4 + 3] = v.w;
    }

    {
        unsigned short xb[16];
#pragma unroll
        for (int j = 0; j < 16; ++j) xb[j] = f2b(x[j]);
        unsigned short* dp = tokb + (size_t)n * H_DIM + lane * 16;
        *(uint4*)(dp)     = *(uint4*)(xb);
        *(uint4*)(dp + 8) = *(uint4*)(xb + 8);
    }

    float acc[N_EXP];
#pragma unroll
    for (int e = 0; e < N_EXP; ++e) {
        const float* wp = router_w + e * H_DIM + lane * 16;
        float s = 0.f;
#pragma unroll
        for (int i = 0; i < 4; ++i) {
            float4 v = *(const float4*)(wp + i * 4);
            s += x[i * 4 + 0] * v.x + x[i * 4 + 1] * v.y
               + x[i * 4 + 2] * v.z + x[i * 4 + 3] * v.w;
        }
        acc[e] = s;
    }

#pragma unroll
    for (int e = 0; e < N_EXP; ++e) {
        float a = acc[e];
#pragma unroll
        for (int off = 32; off > 0; off >>= 1) a += __shfl_xor(a, off);
        acc[e] = a;
    }

    if (lane == 0) {
        float lg[N_EXP];
#pragma unroll
        for (int e = 0; e < N_EXP; ++e) lg[e] = acc[e] + router_b[e];
        int e0 = 0;
#pragma unroll
        for (int e = 1; e < N_EXP; ++e) if (lg[e] > lg[e0]) e0 = e;
        int e1 = -1;
#pragma unroll
        for (int e = 0; e < N_EXP; ++e) {
            if (e == e0) continue;
            if (e1 < 0 || lg[e] > lg[e1]) e1 = e;
        }
        // collapsed weights: w0 = p0/(p0+p1) = sigmoid(l0-l1); eps terms < fp32 ulp
        float w0 = 1.f / (1.f + __expf(lg[e1] - lg[e0]));
        float w1 = 1.f - w0;
        sel[n] = e0 | (e1 << 4);
        w_arr[n * 2] = w0;
        w_arr[n * 2 + 1] = w1;
    }
}

// ---------------- K1b: counting sort, one block per expert (deterministic) ----------------
__global__ __launch_bounds__(256) void k_scan(
    const int* __restrict__ sel, int* __restrict__ cnt, int* __restrict__ bucket)
{
    __shared__ int ssel[N_TOK + N_TOK / 32];   // padded: idx n -> n + (n>>5)
    __shared__ int sc[256];
    const int e = blockIdx.x;
    const int t = threadIdx.x;
#pragma unroll
    for (int i = 0; i < 32; ++i) {
        int n = i * 256 + t;
        ssel[n + (n >> 5)] = sel[n];
    }
    __syncthreads();
    const int base = t * 32;
    int c = 0;
#pragma unroll
    for (int i = 0; i < 32; ++i) {
        int n = base + i;
        int s = ssel[n + (n >> 5)];
        c += ((s & 15) == e) + (((s >> 4) & 15) == e);
    }
    sc[t] = c;
    __syncthreads();
    for (int off = 1; off < 256; off <<= 1) {
        int v = (t >= off) ? sc[t - off] : 0;
        __syncthreads();
        sc[t] += v;
        __syncthreads();
    }
    int pos = sc[t] - c;   // exclusive prefix
    if (t == 255) cnt[e] = sc[255];
#pragma unroll
    for (int i = 0; i < 32; ++i) {
        int n = base + i;
        int s = ssel[n + (n >> 5)];
        if ((s & 15) == e)        bucket[e * N_TOK + pos++] = 2 * n;
        if (((s >> 4) & 15) == e) bucket[e * N_TOK + pos++] = 2 * n + 1;
    }
}

// ---------------- K3: grouped GEMM, plain bf16 Y stores (no atomics) ----------------
// Y row layout (per 128-col segment nt): stored index s = wc*64 + m_lane*4 + j
// holds actual col wc*64 + j*16 + m_lane.
__global__ __launch_bounds__(256, 4) void k_gemm(
    const unsigned short* __restrict__ tokb,
    const unsigned short* __restrict__ Bp,
    const int* __restrict__ cnt, const int* __restrict__ bucket,
    unsigned short* __restrict__ Y)
{
    // flat grid: bid = tile*8 + nt; decode (e, mt) from cnt[] prefix
    const int nt = blockIdx.x & 7;
    const int tile = blockIdx.x >> 3;
    int base = 0, e = 0, mt = -1;
#pragma unroll
    for (int ee = 0; ee < 8; ++ee) {
        int te = (cnt[ee] + 127) >> 7;
        if (tile >= base && tile < base + te) { e = ee; mt = tile - base; }
        base += te;
    }
    if (mt < 0) return;
    const int cnt_local = cnt[e] - mt * 128;

    // As: flat [row][64], XOR-swizzled: (row, part) lives at row*64 + (part^(row&7))*8
    __shared__ __align__(16) unsigned short Asm[128 * 64];
    __shared__ __align__(16) unsigned short Bsm[8 * 128 * 8];  // chunk (kg,d) at (kg*128+d)*8
    __shared__ int rows[128];

    const int t = threadIdx.x;
    if (t < 128)
        rows[t] = (t < cnt_local) ? bucket[e * N_TOK + mt * 128 + t] : -1;
    __syncthreads();

    const int wv = t >> 6, lane = t & 63;
    const int d0 = nt * 128;

    // A staging: instr i, lane l covers LDS chunk c = i*256+wv*64+l
    // -> row r = c>>3 = i*32+wv*8+(l>>3), swizzled slot l&7 holds global part p=(l&7)^(r&7)
    const int p_sw = (lane & 7) ^ ((lane >> 3) & 7);
    const unsigned short* aptr[4];
#pragma unroll
    for (int i = 0; i < 4; ++i) {
        int r = i * 32 + wv * 8 + (lane >> 3);
        int rid = rows[r];
        int tok = (rid >= 0) ? (rid >> 1) : 0;   // inactive rows read token 0; masked at store
        aptr[i] = tokb + (size_t)tok * H_DIM + p_sw * 8;
    }
    // B staging: chunk c = i*256+t -> kg' = c>>7 = i*2+(t>>7), d = t&127
    const unsigned short* bbase = Bp
        + ((size_t)(e * 128 + (t >> 7)) * H_DIM + d0 + (t & 127)) * 8;

    const int w_row = wv >> 1, w_col = wv & 1;
    const int m_lane = lane & 15, quad = lane >> 4;
    const int r7 = m_lane & 7;

    floatx4 acc[4][4];
#pragma unroll
    for (int i = 0; i < 4; ++i)
#pragma unroll
        for (int j = 0; j < 4; ++j) acc[i][j] = (floatx4){0.f, 0.f, 0.f, 0.f};

    for (int kt = 0; kt < H_DIM / 64; ++kt) {
#pragma unroll
        for (int i = 0; i < 4; ++i) {
            __builtin_amdgcn_global_load_lds(
                (GV*)(aptr[i] + kt * 64),
                (LV*)(&Asm[i * 2048 + wv * 512]), 16, 0, 0);
            __builtin_amdgcn_global_load_lds(
                (GV*)(bbase + (size_t)i * 16384 + (size_t)kt * 65536),
                (LV*)(&Bsm[i * 2048 + wv * 512]), 16, 0, 0);
        }
        __syncthreads();

#pragma unroll
        for (int s = 0; s < 2; ++s) {
            bf16x8 a[4], b[4];
#pragma unroll
            for (int i = 0; i < 4; ++i) {
                int row = w_row * 64 + i * 16 + m_lane;
                a[i] = *(const bf16x8*)&Asm[row * 64 + ((s * 4 + quad) ^ r7) * 8];
            }
#pragma unroll
            for (int j = 0; j < 4; ++j)
                b[j] = *(const bf16x8*)&Bsm[((s * 4 + quad) * 128 + w_col * 64 + j * 16 + m_lane) * 8];
#pragma unroll
            for (int i = 0; i < 4; ++i)
#pragma unroll
                for (int j = 0; j < 4; ++j)
                    acc[i][j] = __builtin_amdgcn_mfma_f32_16x16x32_bf16(a[i], b[j], acc[i][j], 0, 0, 0);
        }
        __syncthreads();
    }

    // epilogue: plain bf16 stores, permuted-within-segment layout (8B per (i,reg))
#pragma unroll
    for (int i = 0; i < 4; ++i) {
        const int lr_base = w_row * 64 + i * 16 + quad * 4;
#pragma unroll
        for (int reg = 0; reg < 4; ++reg) {
            const int lr = lr_base + reg;
            const int rid = rows[lr];
            if (rid >= 0) {
                unsigned short v[4];
#pragma unroll
                for (int j = 0; j < 4; ++j) v[j] = f2b(acc[i][j][reg]);
                *(uint2*)(Y + (size_t)rid * H_DIM + d0 + w_col * 64 + m_lane * 4) = *(uint2*)v;
            }
        }
    }
}

// ---------------- K4: combine out[n][d] = w0*Y[2n][s(d)] + w1*Y[2n+1][s(d)] ----------------
__global__ __launch_bounds__(256) void k_combine(
    const unsigned short* __restrict__ Y, const float* __restrict__ w_arr,
    float* __restrict__ out)
{
    const int g = blockIdx.x * 256 + threadIdx.x;   // 1,048,576 threads
    const int n = g >> 7;
    const int c = (g & 127) * 8;                    // 8 consecutive stored shorts
    const unsigned short* y0 = Y + (size_t)(2 * n) * H_DIM + c;
    const unsigned short* y1 = y0 + H_DIM;
    uint4 a = *(const uint4*)y0;
    uint4 b = *(const uint4*)y1;
    const unsigned short* pa = (const unsigned short*)&a;
    const unsigned short* pb = (const unsigned short*)&b;
    const float w0 = w_arr[2 * n], w1 = w_arr[2 * n + 1];
    const int seg = c >> 7;          // nt
    const int sl0 = c & 127;
    float* op = out + (size_t)n * H_DIM + seg * 128;
#pragma unroll
    for (int k = 0; k < 8; ++k) {
        int sl = sl0 + k;
        int wc = sl >> 6, m = (sl >> 2) & 15, j = sl & 3;
        int d = wc * 64 + j * 16 + m;
        op[d] = w0 * b2f(pa[k]) + w1 * b2f(pb[k]);
    }
}

extern "C" void kernel_launch(void* const* d_in, const int* in_sizes, int n_in,
                              void* d_out, int out_size, void* d_ws, size_t ws_size,
                              hipStream_t stream)
{
    const float* tokens   = (const float*)d_in[0]; // fp32 [8192,1024]
    const float* router_w = (const float*)d_in[1]; // fp32 [8,1024]
    const float* router_b = (const float*)d_in[2]; // fp32 [8]
    const float* W        = (const float*)d_in[3]; // fp32 [8,1024,1024]
    float* out = (float*)d_out;                    // fp32 [8192,1024]

    char* ws = (char*)d_ws;
    int*   cnt    = (int*)(ws);                        // 32 B
    int*   sel    = (int*)(ws + 1024);                 // 32 KB
    float* w_arr  = (float*)(ws + 34816);              // 64 KB
    int*   bucket = (int*)(ws + 100352);               // 256 KB
    unsigned short* tokb = (unsigned short*)(ws + 362496);    // 16 MB bf16 tokens  [ends 17139712]
    unsigned short* Bp   = (unsigned short*)(ws + 17139712);  // 16 MB packed bf16 W [ends 33916928]
    unsigned short* Y    = (unsigned short*)(ws + 33916928);  // 32 MB bf16 per-slot outputs (AFTER Bp!)

    k_front  <<<2048 + 1024, 256, 0, stream>>>(tokens, router_w, router_b, W,
                                               sel, w_arr, tokb, Bp);
    k_scan   <<<N_EXP, 256, 0, stream>>>(sel, cnt, bucket);
    k_gemm   <<<MAX_TILES * 8, 256, 0, stream>>>(tokb, Bp, cnt, bucket, Y);
    k_combine<<<N_TOK * (H_DIM / 8) / 256, 256, 0, stream>>>(Y, w_arr, out);
}